// Round 1
// baseline (466.986 us; speedup 1.0000x reference)
//
#include <hip/hip_runtime.h>
#include <math.h>

#define HH 384
#define WW 384
#define HPW 377          // Hp = Wp = 384 - 8 + 1
#define NRD 95           // number of reference positions per dim (stride 4)
#define NGRP (NRD*NRD)   // 9025 groups
#define NCAND 81         // 9x9 search candidates
#define KK 16            // group size
#define NPIX (HH*WW)
#define FINF 3.4e38f

__device__ __forceinline__ int iclip(int v, int hi) {
  return v < 0 ? 0 : (v > hi ? hi : v);
}

// DCT-II orthonormal matrix, computed in double to match numpy then cast f32.
__device__ __forceinline__ void fill_dct(float* D, int t) {
  if (t < 64) {
    int k = t >> 3, i = t & 7;
    double v = cos(M_PI * (2.0 * i + 1.0) * (double)k / 16.0) * 0.5; // sqrt(2/8)=0.5
    if (k == 0) v = v / sqrt(2.0);
    D[t] = (float)v;
  }
}

// ---- 3D transform passes (16 patches of 8x8 in a [1024] LDS buffer) ----
// forward: coef = D g D^T ; element e = k*64 + a*8 + d

__device__ __forceinline__ void pass_colF(const float* __restrict__ in,
                                          float* __restrict__ out,
                                          const float* __restrict__ D, int t) {
  for (int e = t; e < 1024; e += 256) {
    int a = (e >> 3) & 7;
    int base = (e & 0x3C0) | (e & 7);      // k*64 + c
    float s = 0.f;
#pragma unroll
    for (int b = 0; b < 8; b++) s += D[(a << 3) + b] * in[base + (b << 3)];
    out[e] = s;
  }
}

__device__ __forceinline__ void pass_rowF(const float* __restrict__ in,
                                          float* __restrict__ out,
                                          const float* __restrict__ D, int t) {
  for (int e = t; e < 1024; e += 256) {
    int d = e & 7;
    int base = e & ~7;                     // k*64 + a*8
    float s = 0.f;
#pragma unroll
    for (int c = 0; c < 8; c++) s += in[base + c] * D[(d << 3) + c];
    out[e] = s;
  }
}

// inverse: g = D^T c D
__device__ __forceinline__ void pass_colI(const float* __restrict__ in,
                                          float* __restrict__ out,
                                          const float* __restrict__ D, int t) {
  for (int e = t; e < 1024; e += 256) {
    int b = (e >> 3) & 7;
    int base = (e & 0x3C0) | (e & 7);      // k*64 + d
    float s = 0.f;
#pragma unroll
    for (int a = 0; a < 8; a++) s += D[(a << 3) + b] * in[base + (a << 3)];
    out[e] = s;
  }
}

__device__ __forceinline__ void pass_rowI(const float* __restrict__ in,
                                          float* __restrict__ out,
                                          const float* __restrict__ D, int t) {
  for (int e = t; e < 1024; e += 256) {
    int c = e & 7;
    int base = e & ~7;                     // k*64 + b*8
    float s = 0.f;
#pragma unroll
    for (int d = 0; d < 8; d++) s += in[base + d] * D[(d << 3) + c];
    out[e] = s;
  }
}

// Hadamard across the group dim: H[g,k] = (-1)^popc(g&k) / 4. Symmetric, so
// forward and inverse are the same operation.
__device__ __forceinline__ void had16(const float* __restrict__ in,
                                      float* __restrict__ out, int t) {
  for (int e = t; e < 1024; e += 256) {
    int g = e >> 6, q = e & 63;
    float s = 0.f;
#pragma unroll
    for (int k = 0; k < 16; k++) {
      float v = in[(k << 6) + q];
      s += (__popc(g & k) & 1) ? -v : v;
    }
    out[e] = 0.25f * s;
  }
}

// ---- block matching: 81 candidates, pick 16 smallest (tie -> lower index) ----
template <typename T>
__device__ void block_match(const T* __restrict__ img, int ri, int rj,
                            float* ref, float* dist, int* seli, int* selj, int t) {
  if (t < 64) ref[t] = (float)img[(ri + (t >> 3)) * WW + rj + (t & 7)];
  __syncthreads();
  if (t < NCAND) {
    int ci = iclip(ri + (t / 9) * 3 - 12, HPW - 1);
    int cj = iclip(rj + (t % 9) * 3 - 12, HPW - 1);
    float scc = 0.f, scr = 0.f, srr = 0.f;
#pragma unroll 8
    for (int p = 0; p < 64; p++) {
      float cv = (float)img[(ci + (p >> 3)) * WW + cj + (p & 7)];
      float rv = ref[p];
      scc += cv * cv; scr += cv * rv; srr += rv * rv;
    }
    dist[t] = scc - 2.f * scr + srr;       // same algebraic form as reference
  }
  __syncthreads();
  if (t == 0) {
    for (int r = 0; r < KK; r++) {
      float best = FINF; int bi = 0;
      for (int c = 0; c < NCAND; c++) {
        float d = dist[c];
        if (d < best) { best = d; bi = c; }   // strict < == lower-index tiebreak
      }
      dist[bi] = FINF;
      seli[r] = iclip(ri + (bi / 9) * 3 - 12, HPW - 1);
      selj[r] = iclip(rj + (bi % 9) * 3 - 12, HPW - 1);
    }
  }
  __syncthreads();
}

// ---- step 1: hard-threshold collaborative filtering ----
__global__ __launch_bounds__(256) void bm3d_step1(
    const int* __restrict__ img, const int* __restrict__ pvar,
    float* __restrict__ num, float* __restrict__ den) {
  __shared__ float D[64], ref[64], dist[NCAND];
  __shared__ int seli[KK], selj[KK];
  __shared__ float A[1024], Tb[1024], Cc[1024];
  __shared__ int redi[256];

  int t = threadIdx.x;
  int n = blockIdx.x;
  int ri = (n / NRD) * 4, rj = (n % NRD) * 4;

  fill_dct(D, t);
  __syncthreads();

  block_match(img, ri, rj, ref, dist, seli, selj, t);

  float sigma2 = (float)pvar[0];
  float sigma = sqrtf(sigma2);
  float thr = 2.7f * sigma;

  // gather group
  for (int e = t; e < 1024; e += 256) {
    int k = e >> 6, p = e & 63;
    A[e] = (float)img[(seli[k] + (p >> 3)) * WW + selj[k] + (p & 7)];
  }
  __syncthreads();

  pass_colF(A, Tb, D, t); __syncthreads();
  pass_rowF(Tb, A, D, t); __syncthreads();
  had16(A, Cc, t);        __syncthreads();

  // hard threshold + nnz
  int cnt = 0;
  for (int e = t; e < 1024; e += 256) {
    float v = Cc[e];
    bool keep = (fabsf(v) > thr) || (e == 0);   // element 0 = (g=0,a=0,d=0) DC
    if (!keep) Cc[e] = 0.f;
    cnt += keep ? 1 : 0;
  }
  redi[t] = cnt;
  __syncthreads();
  for (int s = 128; s > 0; s >>= 1) {
    if (t < s) redi[t] += redi[t + s];
    __syncthreads();
  }
  float w = 1.f / (sigma2 * fmaxf((float)redi[0], 1.f));

  had16(Cc, A, t);        __syncthreads();
  pass_colI(A, Tb, D, t); __syncthreads();
  pass_rowI(Tb, A, D, t); __syncthreads();

  for (int e = t; e < 1024; e += 256) {
    int k = e >> 6, p = e & 63;
    int pix = (seli[k] + (p >> 3)) * WW + selj[k] + (p & 7);
    atomicAdd(&num[pix], w * A[e]);
    atomicAdd(&den[pix], w);
  }
}

// ---- step 2: Wiener filtering using the basic estimate ----
__global__ __launch_bounds__(256) void bm3d_step2(
    const int* __restrict__ img, const float* __restrict__ basic,
    const int* __restrict__ pvar,
    float* __restrict__ num, float* __restrict__ den) {
  __shared__ float D[64], ref[64], dist[NCAND];
  __shared__ int seli[KK], selj[KK];
  __shared__ float A[1024], Tb[1024], Cc[1024];
  __shared__ float redf[256];

  int t = threadIdx.x;
  int n = blockIdx.x;
  int ri = (n / NRD) * 4, rj = (n % NRD) * 4;

  fill_dct(D, t);
  __syncthreads();

  block_match(basic, ri, rj, ref, dist, seli, selj, t);

  float sigma2 = (float)pvar[0];

  // cb: forward 3D transform of BASIC group -> Cc
  for (int e = t; e < 1024; e += 256) {
    int k = e >> 6, p = e & 63;
    A[e] = basic[(seli[k] + (p >> 3)) * WW + selj[k] + (p & 7)];
  }
  __syncthreads();
  pass_colF(A, Tb, D, t); __syncthreads();
  pass_rowF(Tb, A, D, t); __syncthreads();
  had16(A, Cc, t);        __syncthreads();

  // cn: forward 3D transform of NOISY group -> Tb
  for (int e = t; e < 1024; e += 256) {
    int k = e >> 6, p = e & 63;
    A[e] = (float)img[(seli[k] + (p >> 3)) * WW + selj[k] + (p & 7)];
  }
  __syncthreads();
  pass_colF(A, Tb, D, t); __syncthreads();
  pass_rowF(Tb, A, D, t); __syncthreads();
  had16(A, Tb, t);        __syncthreads();    // cn now in Tb, A free

  // Wiener shrinkage
  float part = 0.f;
  for (int e = t; e < 1024; e += 256) {
    float cb = Cc[e];
    float we = cb * cb / (cb * cb + sigma2);
    A[e] = we * Tb[e];
    part += we * we;
  }
  redf[t] = part;
  __syncthreads();
  for (int s = 128; s > 0; s >>= 1) {
    if (t < s) redf[t] += redf[t + s];
    __syncthreads();
  }
  float w = 1.f / (sigma2 * fmaxf(redf[0], 1e-8f));

  had16(A, Cc, t);        __syncthreads();
  pass_colI(Cc, Tb, D, t); __syncthreads();
  pass_rowI(Tb, A, D, t);  __syncthreads();

  for (int e = t; e < 1024; e += 256) {
    int k = e >> 6, p = e & 63;
    int pix = (seli[k] + (p >> 3)) * WW + selj[k] + (p & 7);
    atomicAdd(&num[pix], w * A[e]);
    atomicAdd(&den[pix], w);
  }
}

__global__ void div_kernel(const float* __restrict__ num,
                           const float* __restrict__ den,
                           float* __restrict__ out, int npix) {
  int i = blockIdx.x * blockDim.x + threadIdx.x;
  if (i < npix) out[i] = num[i] / fmaxf(den[i], 1e-8f);
}

extern "C" void kernel_launch(void* const* d_in, const int* in_sizes, int n_in,
                              void* d_out, int out_size, void* d_ws, size_t ws_size,
                              hipStream_t stream) {
  const int* img  = (const int*)d_in[0];
  const int* pvar = (const int*)d_in[1];
  float* out = (float*)d_out;
  float* ws  = (float*)d_ws;

  float* num1  = ws + 0 * NPIX;
  float* den1  = ws + 1 * NPIX;
  float* basic = ws + 2 * NPIX;
  float* num2  = ws + 3 * NPIX;
  float* den2  = ws + 4 * NPIX;

  hipMemsetAsync(num1, 0, (size_t)2 * NPIX * sizeof(float), stream); // num1+den1
  hipMemsetAsync(num2, 0, (size_t)2 * NPIX * sizeof(float), stream); // num2+den2

  bm3d_step1<<<NGRP, 256, 0, stream>>>(img, pvar, num1, den1);
  div_kernel<<<(NPIX + 255) / 256, 256, 0, stream>>>(num1, den1, basic, NPIX);
  bm3d_step2<<<NGRP, 256, 0, stream>>>(img, basic, pvar, num2, den2);
  div_kernel<<<(NPIX + 255) / 256, 256, 0, stream>>>(num2, den2, out, NPIX);
}

// Round 2
// 372.732 us; speedup vs baseline: 1.2529x; 1.2529x over previous
//
#include <hip/hip_runtime.h>
#include <math.h>

#define WW 384
#define HPW 377          // Hp = Wp = 384 - 8 + 1
#define NRD 95           // reference positions per dim (stride 4)
#define NGRP (NRD*NRD)   // 9025 groups
#define NPIX (384*384)
#define FINF 3.4e38f

__device__ __forceinline__ int iclip(int v, int hi) {
  return v < 0 ? 0 : (v > hi ? hi : v);
}

// DCT-II orthonormal matrix in double (matches numpy f64 -> f32 cast).
__device__ __forceinline__ void fill_D(float* D, int t) {
  if (t < 64) {
    int k = t >> 3, i = t & 7;
    double v = cos(M_PI * (2.0 * i + 1.0) * (double)k / 16.0) * 0.5;
    if (k == 0) v = v / sqrt(2.0);
    D[t] = (float)v;
  }
}

template <typename T>
__device__ __forceinline__ void load_tile(const T* __restrict__ img, int bi, int bj,
                                          float* __restrict__ tile, int t) {
#pragma unroll
  for (int i = 0; i < 8; i++) {
    int e = t + (i << 7);
    int r = e >> 5, c = e & 31;
    tile[e] = (float)img[(bi + r) * WW + bj + c];
  }
}

// 81 candidate distances, same algebraic form as reference (exact ints in step 1)
__device__ __forceinline__ void compute_dist(const float* __restrict__ tile,
                                             const float* __restrict__ ref,
                                             int ri, int rj, int bi, int bj,
                                             float* __restrict__ dist, int t) {
  if (t < 81) {
    int ci = iclip(ri + (t / 9) * 3 - 12, HPW - 1) - bi;
    int cj = iclip(rj + (t % 9) * 3 - 12, HPW - 1) - bj;
    const float* cp = tile + ci * 32 + cj;
    float scc = 0.f, scr = 0.f, srr = 0.f;
#pragma unroll
    for (int i = 0; i < 8; i++)
#pragma unroll
      for (int j = 0; j < 8; j++) {
        float cv = cp[i * 32 + j];
        float rv = ref[i * 8 + j];
        scc += cv * cv; scr += cv * rv; srr += rv * rv;
      }
    dist[t] = scc - 2.f * scr + srr;
  }
}

// wave-0 parallel top-16: 16 rounds of 64-lane argmin (tie -> lower index)
__device__ __forceinline__ void select16(const float* __restrict__ dist, int ri, int rj,
                                         int* __restrict__ sel_i, int* __restrict__ sel_j,
                                         int t) {
  if (t < 64) {
    float d0 = dist[t];
    float d1 = (t + 64 < 81) ? dist[t + 64] : FINF;
    int i0 = t, i1 = t + 64;
#pragma unroll 1
    for (int r = 0; r < 16; r++) {
      float d = d0; int i = i0;
      if (d1 < d0) { d = d1; i = i1; }
#pragma unroll
      for (int m = 1; m < 64; m <<= 1) {
        float dd = __shfl_xor(d, m);
        int   ii = __shfl_xor(i, m);
        if (dd < d || (dd == d && ii < i)) { d = dd; i = ii; }
      }
      if (t == 0) {
        sel_i[r] = iclip(ri + (i / 9) * 3 - 12, HPW - 1);
        sel_j[r] = iclip(rj + (i % 9) * 3 - 12, HPW - 1);
      }
      if (i == i0) d0 = FINF;
      if (i == i1) d1 = FINF;
    }
  }
}

// gather 16 selected 8x8 patches from tile into X, layout L0 = [k][b][c]
__device__ __forceinline__ void gather(const float* __restrict__ tile,
                                       const int* __restrict__ sel_i,
                                       const int* __restrict__ sel_j,
                                       int bi, int bj, float* __restrict__ X, int t) {
  int k = t >> 3, b = t & 7;
  const float* src = tile + (sel_i[k] - bi + b) * 32 + (sel_j[k] - bj);
  float* dst = X + k * 64 + b * 8;
#pragma unroll
  for (int cc = 0; cc < 8; cc++) {
    int c = (cc + t) & 7;                     // rotate to spread LDS banks
    dst[c] = src[c];
  }
}

// one separable-DCT pass: thread owns output index o = t&7 (M-row in regs),
// tasks = rows s+16j; OUT_O_MAJOR picks the transposed-write layout.
template <bool OUT_O_MAJOR>
__device__ __forceinline__ void dct_pass(const float* __restrict__ in,
                                         float* __restrict__ out,
                                         const float* __restrict__ M, int t) {
  int o = t & 7, s = t >> 3;
  float4 ma = *(const float4*)(M + o * 8);
  float4 mb = *(const float4*)(M + o * 8 + 4);
#pragma unroll
  for (int j = 0; j < 8; j++) {
    int task = s + (j << 4);
    float4 xa = *(const float4*)(in + task * 8);
    float4 xb = *(const float4*)(in + task * 8 + 4);
    float acc = xa.x * ma.x + xa.y * ma.y + xa.z * ma.z + xa.w * ma.w
              + xb.x * mb.x + xb.y * mb.y + xb.z * mb.z + xb.w * mb.w;
    int k = task >> 3, r = task & 7;
    out[OUT_O_MAJOR ? (k * 64 + o * 8 + r) : (k * 64 + r * 8 + o)] = acc;
  }
}

// 16-point Walsh-Hadamard (natural order) in registers; scale 1/4.
__device__ __forceinline__ void had_pass(const float* __restrict__ in,
                                         float* __restrict__ out, int t) {
  if (t < 64) {
    float v[16];
#pragma unroll
    for (int k = 0; k < 16; k++) v[k] = in[(k << 6) + t];
#pragma unroll
    for (int s = 1; s < 16; s <<= 1)
#pragma unroll
      for (int i = 0; i < 16; i++)
        if (!(i & s)) { float a = v[i], b = v[i | s]; v[i] = a + b; v[i | s] = a - b; }
#pragma unroll
    for (int g = 0; g < 16; g++) out[(g << 6) + t] = 0.25f * v[g];
  }
}

__device__ __forceinline__ float block_sum(float x, float* red2, int t) {
#pragma unroll
  for (int m = 1; m < 64; m <<= 1) x += __shfl_xor(x, m);
  if ((t & 63) == 0) red2[t >> 6] = x;
  __syncthreads();
  return red2[0] + red2[1];
}

// ---- step 1: hard-threshold collaborative filtering ----
__global__ __launch_bounds__(128) void bm3d_step1(
    const int* __restrict__ img, const int* __restrict__ pvar,
    float* __restrict__ num, float* __restrict__ den) {
  __shared__ float D[64], DT[64], ref[64], dist[81];
  __shared__ int sel_i[16], sel_j[16];
  __shared__ float tA[1024], tB[1024], X[1024], Y[1024];
  __shared__ float red2[2];

  int t = threadIdx.x;
  int n = blockIdx.x;
  int ri = (n / NRD) * 4, rj = (n % NRD) * 4;
  int bi = ri - 12 < 0 ? 0 : (ri - 12 > 352 ? 352 : ri - 12);
  int bj = rj - 12 < 0 ? 0 : (rj - 12 > 352 ? 352 : rj - 12);

  fill_D(D, t);
  load_tile(img, bi, bj, tA, t);
  __syncthreads();

  if (t < 64) {
    DT[t] = D[((t & 7) << 3) | (t >> 3)];
    ref[t] = tA[(ri - bi + (t >> 3)) * 32 + (rj - bj) + (t & 7)];
  }
  __syncthreads();

  compute_dist(tA, ref, ri, rj, bi, bj, dist, t);
  __syncthreads();
  select16(dist, ri, rj, sel_i, sel_j, t);
  __syncthreads();

  gather(tA, sel_i, sel_j, bi, bj, X, t);
  __syncthreads();

  dct_pass<true>(X, Y, D, t);  __syncthreads();   // contract c -> [k][d][b]
  dct_pass<true>(Y, X, D, t);  __syncthreads();   // contract b -> [k][a*8+d]
  had_pass(X, Y, t);           __syncthreads();   // fwd Hadamard -> [g][q]

  float sigma2 = (float)pvar[0];
  float thr = 2.7f * sqrtf(sigma2);
  float cnt = 0.f;
#pragma unroll
  for (int i = 0; i < 8; i++) {
    int p = t + (i << 7);
    float v = Y[p];
    bool keep = (fabsf(v) > thr) || (p == 0);     // p==0 is (g=0,a=0,d=0)
    if (!keep) Y[p] = 0.f;
    cnt += keep ? 1.f : 0.f;
  }
  float nnz = block_sum(cnt, red2, t);            // has a syncthreads inside
  float w = 1.f / (sigma2 * fmaxf(nnz, 1.f));

  had_pass(Y, X, t);            __syncthreads();  // inv Hadamard -> [k][a*8+d]
  dct_pass<true>(X, Y, DT, t);  __syncthreads();  // contract d -> [k][c*8+a]
  dct_pass<false>(Y, X, DT, t); __syncthreads();  // contract a -> [k][c*8+b]

  // zero LDS accumulators (tA/tB free now)
#pragma unroll
  for (int i = 0; i < 8; i++) { int p = t + (i << 7); tA[p] = 0.f; tB[p] = 0.f; }
  __syncthreads();

#pragma unroll
  for (int i = 0; i < 8; i++) {
    int e = t + (i << 7);
    int k = e >> 6, c = (e >> 3) & 7, b = e & 7;
    float v = X[e];
    int toff = (sel_i[k] - bi + b) * 32 + (sel_j[k] - bj + c);
    atomicAdd(&tA[toff], w * v);
    atomicAdd(&tB[toff], w);
  }
  __syncthreads();

#pragma unroll
  for (int i = 0; i < 8; i++) {
    int p = t + (i << 7);
    float dv = tB[p];
    if (dv != 0.f) {
      int gp = (bi + (p >> 5)) * WW + bj + (p & 31);
      atomicAdd(&num[gp], tA[p]);
      atomicAdd(&den[gp], dv);
    }
  }
}

// ---- step 2: Wiener filtering using the basic estimate ----
__global__ __launch_bounds__(128) void bm3d_step2(
    const int* __restrict__ img, const float* __restrict__ basic,
    const int* __restrict__ pvar,
    float* __restrict__ num, float* __restrict__ den) {
  __shared__ float D[64], DT[64], ref[64], dist[81];
  __shared__ int sel_i[16], sel_j[16];
  __shared__ float tA[1024], tB[1024], X[1024], Y[1024];
  __shared__ float red2[2];

  int t = threadIdx.x;
  int n = blockIdx.x;
  int ri = (n / NRD) * 4, rj = (n % NRD) * 4;
  int bi = ri - 12 < 0 ? 0 : (ri - 12 > 352 ? 352 : ri - 12);
  int bj = rj - 12 < 0 ? 0 : (rj - 12 > 352 ? 352 : rj - 12);

  fill_D(D, t);
  load_tile(basic, bi, bj, tA, t);
  load_tile(img,   bi, bj, tB, t);
  __syncthreads();

  if (t < 64) {
    DT[t] = D[((t & 7) << 3) | (t >> 3)];
    ref[t] = tA[(ri - bi + (t >> 3)) * 32 + (rj - bj) + (t & 7)];
  }
  __syncthreads();

  compute_dist(tA, ref, ri, rj, bi, bj, dist, t);
  __syncthreads();
  select16(dist, ri, rj, sel_i, sel_j, t);
  __syncthreads();

  // cb = fwd3d(basic group) -> Y
  gather(tA, sel_i, sel_j, bi, bj, X, t);
  __syncthreads();
  dct_pass<true>(X, Y, D, t);  __syncthreads();
  dct_pass<true>(Y, X, D, t);  __syncthreads();
  had_pass(X, Y, t);           __syncthreads();   // cb in Y

  // cn = fwd3d(noisy group) -> tA (tile no longer needed)
  gather(tB, sel_i, sel_j, bi, bj, X, t);
  __syncthreads();
  dct_pass<true>(X, tA, D, t); __syncthreads();
  dct_pass<true>(tA, X, D, t); __syncthreads();
  had_pass(X, tA, t);          __syncthreads();   // cn in tA

  float sigma2 = (float)pvar[0];
  float ws = 0.f;
#pragma unroll
  for (int i = 0; i < 8; i++) {
    int p = t + (i << 7);
    float cb = Y[p];
    float we = cb * cb / (cb * cb + sigma2);
    X[p] = we * tA[p];
    ws += we * we;
  }
  float wsum = block_sum(ws, red2, t);            // syncthreads inside
  float w = 1.f / (sigma2 * fmaxf(wsum, 1e-8f));

  had_pass(X, Y, t);            __syncthreads();
  dct_pass<true>(Y, X, DT, t);  __syncthreads();
  dct_pass<false>(X, Y, DT, t); __syncthreads();  // result in Y, layout [k][c*8+b]

#pragma unroll
  for (int i = 0; i < 8; i++) { int p = t + (i << 7); tA[p] = 0.f; tB[p] = 0.f; }
  __syncthreads();

#pragma unroll
  for (int i = 0; i < 8; i++) {
    int e = t + (i << 7);
    int k = e >> 6, c = (e >> 3) & 7, b = e & 7;
    float v = Y[e];
    int toff = (sel_i[k] - bi + b) * 32 + (sel_j[k] - bj + c);
    atomicAdd(&tA[toff], w * v);
    atomicAdd(&tB[toff], w);
  }
  __syncthreads();

#pragma unroll
  for (int i = 0; i < 8; i++) {
    int p = t + (i << 7);
    float dv = tB[p];
    if (dv != 0.f) {
      int gp = (bi + (p >> 5)) * WW + bj + (p & 31);
      atomicAdd(&num[gp], tA[p]);
      atomicAdd(&den[gp], dv);
    }
  }
}

__global__ void div_kernel(const float* __restrict__ num,
                           const float* __restrict__ den,
                           float* __restrict__ out, int npix) {
  int i = blockIdx.x * blockDim.x + threadIdx.x;
  if (i < npix) out[i] = num[i] / fmaxf(den[i], 1e-8f);
}

extern "C" void kernel_launch(void* const* d_in, const int* in_sizes, int n_in,
                              void* d_out, int out_size, void* d_ws, size_t ws_size,
                              hipStream_t stream) {
  const int* img  = (const int*)d_in[0];
  const int* pvar = (const int*)d_in[1];
  float* out = (float*)d_out;
  float* ws  = (float*)d_ws;

  float* num1  = ws + 0 * NPIX;
  float* den1  = ws + 1 * NPIX;
  float* basic = ws + 2 * NPIX;
  float* num2  = ws + 3 * NPIX;
  float* den2  = ws + 4 * NPIX;

  hipMemsetAsync(num1, 0, (size_t)2 * NPIX * sizeof(float), stream);
  hipMemsetAsync(num2, 0, (size_t)2 * NPIX * sizeof(float), stream);

  bm3d_step1<<<NGRP, 128, 0, stream>>>(img, pvar, num1, den1);
  div_kernel<<<(NPIX + 255) / 256, 256, 0, stream>>>(num1, den1, basic, NPIX);
  bm3d_step2<<<NGRP, 128, 0, stream>>>(img, basic, pvar, num2, den2);
  div_kernel<<<(NPIX + 255) / 256, 256, 0, stream>>>(num2, den2, out, NPIX);
}

// Round 3
// 297.239 us; speedup vs baseline: 1.5711x; 1.2540x over previous
//
#include <hip/hip_runtime.h>
#include <math.h>

#define TS 45            // LDS tile stride (32 rows x 44 used cols, +1 pad)
#define FINF 3.4e38f

__device__ __forceinline__ int iclip(int v, int hi) {
  return v < 0 ? 0 : (v > hi ? hi : v);
}

// Exact f32 values of the reference D8 (computed in f64, cast to f32).
constexpr float CA = 0.35355339059327373f; // 1/(2*sqrt(2))
constexpr float K1 = 0.49039264020161522f; // cos(1*pi/16)/2
constexpr float K2 = 0.46193976625564337f; // cos(2*pi/16)/2
constexpr float K3 = 0.41573480615127262f; // cos(3*pi/16)/2
constexpr float K4 = 0.35355339059327379f; // cos(4*pi/16)/2
constexpr float K5 = 0.27778511650980111f; // cos(5*pi/16)/2
constexpr float K6 = 0.19134171618254489f; // cos(6*pi/16)/2
constexpr float K7 = 0.097545161008064135f;// cos(7*pi/16)/2

constexpr float DCT8[8][8] = {
  { CA, CA, CA, CA, CA, CA, CA, CA},
  { K1, K3, K5, K7,-K7,-K5,-K3,-K1},
  { K2, K6,-K6,-K2,-K2,-K6, K6, K2},
  { K3,-K7,-K1,-K5, K5, K1, K7,-K3},
  { K4,-K4,-K4, K4, K4,-K4,-K4, K4},
  { K5,-K1, K7, K3,-K3,-K7, K1,-K5},
  { K6,-K2, K2,-K6,-K6, K2,-K2, K6},
  { K7,-K5, K3,-K1, K1,-K3, K5,-K7},
};

// lane-xor exchange: DPP for 1/2, ds_swizzle for 4/8/16, shfl for 32
__device__ __forceinline__ int sxor_i(int v, int m) {
  switch (m) {
    case 1:  return __builtin_amdgcn_update_dpp(0, v, 0xB1, 0xF, 0xF, true); // quad_perm [1,0,3,2]
    case 2:  return __builtin_amdgcn_update_dpp(0, v, 0x4E, 0xF, 0xF, true); // quad_perm [2,3,0,1]
    case 4:  return __builtin_amdgcn_ds_swizzle(v, (4 << 10) | 0x1F);
    case 8:  return __builtin_amdgcn_ds_swizzle(v, (8 << 10) | 0x1F);
    case 16: return __builtin_amdgcn_ds_swizzle(v, (16 << 10) | 0x1F);
    default: return __shfl_xor(v, 32, 64);
  }
}
__device__ __forceinline__ float sxor_f(float v, int m) {
  return __int_as_float(sxor_i(__float_as_int(v), m));
}

// broadcast from quad lane s (VALU DPP, no LDS pipe)
__device__ __forceinline__ float qbcast(float v, int s) {
  int x = __float_as_int(v), r;
  switch (s) {
    case 0:  r = __builtin_amdgcn_update_dpp(0, x, 0x00, 0xF, 0xF, true); break;
    case 1:  r = __builtin_amdgcn_update_dpp(0, x, 0x55, 0xF, 0xF, true); break;
    case 2:  r = __builtin_amdgcn_update_dpp(0, x, 0xAA, 0xF, 0xF, true); break;
    default: r = __builtin_amdgcn_update_dpp(0, x, 0xFF, 0xF, 0xF, true); break;
  }
  return __int_as_float(r);
}

// forward: row DCT (lane-local, literal coeffs) then column DCT (quad mix)
__device__ __forceinline__ void fwd_rowcol(float X[2][8], float U[2][8],
                                           const float Ca0[8], const float Ca1[8]) {
#pragma unroll
  for (int r = 0; r < 2; r++)
#pragma unroll
    for (int d = 0; d < 8; d++) {
      float s = X[r][0] * DCT8[d][0];
#pragma unroll
      for (int c = 1; c < 8; c++) s += X[r][c] * DCT8[d][c];
      U[r][d] = s;
    }
#pragma unroll
  for (int r = 0; r < 2; r++)
#pragma unroll
    for (int d = 0; d < 8; d++) X[r][d] = 0.f;
#pragma unroll
  for (int b = 0; b < 8; b++)
#pragma unroll
    for (int d = 0; d < 8; d++) {
      float yb = qbcast(U[b & 1][d], b >> 1);
      X[0][d] += Ca0[b] * yb;
      X[1][d] += Ca1[b] * yb;
    }
}

// inverse: column (quad mix, D^T coeffs) then row (lane-local literals)
__device__ __forceinline__ void inv_colrow(float X[2][8], float U[2][8],
                                           const float Ct0[8], const float Ct1[8]) {
#pragma unroll
  for (int r = 0; r < 2; r++)
#pragma unroll
    for (int d = 0; d < 8; d++) U[r][d] = 0.f;
#pragma unroll
  for (int a = 0; a < 8; a++)
#pragma unroll
    for (int d = 0; d < 8; d++) {
      float za = qbcast(X[a & 1][d], a >> 1);
      U[0][d] += Ct0[a] * za;
      U[1][d] += Ct1[a] * za;
    }
#pragma unroll
  for (int r = 0; r < 2; r++)
#pragma unroll
    for (int c = 0; c < 8; c++) {
      float s = U[r][0] * DCT8[0][c];
#pragma unroll
      for (int d = 1; d < 8; d++) s += U[r][d] * DCT8[d][c];
      X[r][c] = s;
    }
}

// 16-point Walsh-Hadamard across lane bits 2..5 (k dim), scale 1/4
__device__ __forceinline__ void had16r(float X[2][8], int lane) {
#pragma unroll
  for (int m = 4; m <= 32; m <<= 1) {
    bool hi = (lane & m) != 0;
#pragma unroll
    for (int r = 0; r < 2; r++)
#pragma unroll
      for (int d = 0; d < 8; d++) {
        float tv = sxor_f(X[r][d], m);
        X[r][d] = hi ? (tv - X[r][d]) : (X[r][d] + tv);
      }
  }
#pragma unroll
  for (int r = 0; r < 2; r++)
#pragma unroll
    for (int d = 0; d < 8; d++) X[r][d] *= 0.25f;
}

template <int WIEN>
__device__ __forceinline__ void group_worker(
    const float* __restrict__ tileS, const float* __restrict__ tileN,
    float* __restrict__ accN, float* __restrict__ accD,
    const float* __restrict__ ldsD, int* __restrict__ sel,
    int lane, int ri, int rj, int bi, int ub, float sigma2) {

  // ---------- block match: 81 candidates, lane holds cand lane and 64+lane ----
  int cB = lane < 17 ? 64 + lane : 80;
  int aiA = iclip(ri + (lane / 9) * 3 - 12, 376) - bi;
  int ajA = iclip(rj + (lane % 9) * 3 - 12, 376) - ub;
  int aiB = iclip(ri + (cB / 9) * 3 - 12, 376) - bi;
  int ajB = iclip(rj + (cB % 9) * 3 - 12, 376) - ub;
  int roi = ri - bi, roj = rj - ub;
  float sccA = 0.f, scrA = 0.f, sccB = 0.f, scrB = 0.f, srr = 0.f;
#pragma unroll
  for (int i = 0; i < 8; i++) {
    const float* rr = tileS + (roi + i) * TS + roj;
    const float* ar = tileS + (aiA + i) * TS + ajA;
    const float* br = tileS + (aiB + i) * TS + ajB;
#pragma unroll
    for (int j = 0; j < 8; j++) {
      float rv = rr[j], av = ar[j], bv = br[j];
      sccA += av * av; scrA += av * rv;
      sccB += bv * bv; scrB += bv * rv;
      srr  += rv * rv;
    }
  }
  float d0 = sccA - 2.f * scrA + srr; int i0 = lane;
  float d1 = lane < 17 ? (sccB - 2.f * scrB + srr) : FINF; int i1 = 64 + lane;

  // ---------- top-16 (tie -> lower candidate index, matches lax.top_k) ------
#pragma unroll 1
  for (int r = 0; r < 16; r++) {
    float d = d0; int i = i0;
    if (d1 < d0) { d = d1; i = i1; }
#pragma unroll
    for (int m = 1; m <= 32; m <<= 1) {
      float dd = sxor_f(d, m); int ii = sxor_i(i, m);
      if (dd < d || (dd == d && ii < i)) { d = dd; i = ii; }
    }
    if (lane == 0) {
      int si = iclip(ri + (i / 9) * 3 - 12, 376) - bi;
      int sj = iclip(rj + (i % 9) * 3 - 12, 376) - ub;
      sel[r] = (si << 8) | sj;
    }
    if (i == i0) d0 = FINF;
    if (i == i1) d1 = FINF;
  }

  // ---------- per-lane geometry + column-DCT coefficient rows ---------------
  int q = lane & 3, k = lane >> 2;
  float Ca0[8], Ca1[8];
#pragma unroll
  for (int b = 0; b < 8; b++) {
    Ca0[b] = ldsD[(2 * q) * 8 + b];
    Ca1[b] = ldsD[(2 * q + 1) * 8 + b];
  }
  int sp = sel[k];
  int gi = (sp >> 8) + 2 * q, gj = sp & 255;

  float X[2][8], U[2][8], ZB[2][8];
  float w;

  if (WIEN) {                      // cb = fwd3d(basic group)
#pragma unroll
    for (int r = 0; r < 2; r++)
#pragma unroll
      for (int c = 0; c < 8; c++) ZB[r][c] = tileS[(gi + r) * TS + gj + c];
    fwd_rowcol(ZB, U, Ca0, Ca1);
    had16r(ZB, lane);
  }

  // cn / noisy group
#pragma unroll
  for (int r = 0; r < 2; r++)
#pragma unroll
    for (int c = 0; c < 8; c++) X[r][c] = tileN[(gi + r) * TS + gj + c];
  fwd_rowcol(X, U, Ca0, Ca1);
  had16r(X, lane);

  if (WIEN) {
    float part = 0.f;
#pragma unroll
    for (int r = 0; r < 2; r++)
#pragma unroll
      for (int d = 0; d < 8; d++) {
        float cb = ZB[r][d];
        float we = cb * cb / (cb * cb + sigma2);
        X[r][d] = we * X[r][d];
        part += we * we;
      }
#pragma unroll
    for (int m = 1; m <= 32; m <<= 1) part += sxor_f(part, m);
    w = 1.f / (sigma2 * fmaxf(part, 1e-8f));
  } else {
    float thr = 2.7f * sqrtf(sigma2);
    int cnt = 0;
#pragma unroll
    for (int r = 0; r < 2; r++)
#pragma unroll
      for (int d = 0; d < 8; d++) {
        bool keep = (fabsf(X[r][d]) > thr) || (lane == 0 && r == 0 && d == 0);
        cnt += (int)__popcll(__ballot(keep));
        if (!keep) X[r][d] = 0.f;
      }
    w = 1.f / (sigma2 * fmaxf((float)cnt, 1.f));
  }

  // ---------- inverse 3D transform ------------------------------------------
  had16r(X, lane);
#pragma unroll
  for (int a = 0; a < 8; a++) {    // D^T rows for this lane's two b's
    Ca0[a] = ldsD[a * 8 + 2 * q];
    Ca1[a] = ldsD[a * 8 + 2 * q + 1];
  }
  inv_colrow(X, U, Ca0, Ca1);

  // ---------- accumulate into shared num/den tiles ---------------------------
#pragma unroll
  for (int r = 0; r < 2; r++)
#pragma unroll
    for (int c = 0; c < 8; c++) {
      int off = (gi + r) * TS + gj + c;
      atomicAdd(&accN[off], w * X[r][c]);
      atomicAdd(&accD[off], w);
    }
}

template <int WIEN>
__global__ __launch_bounds__(256, 5) void bm3d_pass(
    const int* __restrict__ img, const float* __restrict__ basic,
    const int* __restrict__ pvar,
    float* __restrict__ num, float* __restrict__ den) {
  __shared__ float ldsD[64];
  __shared__ int   ldsSel[4][16];
  __shared__ float tileN[32 * TS];
  __shared__ float tileB[WIEN ? 32 * TS : 1];
  __shared__ float accN[32 * TS], accD[32 * TS];

  int t = threadIdx.x;
  int brow = blockIdx.x / 24, bcb = blockIdx.x - brow * 24;
  int ri = brow * 4;
  int bim = ri - 12;      int bi = bim < 0 ? 0 : (bim > 352 ? 352 : bim);
  int ubm = 16 * bcb - 12; int ub = ubm < 0 ? 0 : (ubm > 352 ? 352 : ubm);

  if (t < 64) ldsD[t] = DCT8[t >> 3][t & 7];
  for (int e = t; e < 32 * 44; e += 256) {
    int r = e / 44, c = e - r * 44;
    int col = ub + c;
    bool ok = col < 384;
    tileN[r * TS + c] = ok ? (float)img[(bi + r) * 384 + col] : 0.f;
    if (WIEN) tileB[r * TS + c] = ok ? basic[(bi + r) * 384 + col] : 0.f;
  }
  for (int e = t; e < 32 * TS; e += 256) { accN[e] = 0.f; accD[e] = 0.f; }
  __syncthreads();

  float sigma2 = (float)pvar[0];
  int wv = t >> 6, lane = t & 63;
  int gc = bcb * 4 + wv;
  if (gc < 95) {
    group_worker<WIEN>(WIEN ? tileB : tileN, tileN, accN, accD, ldsD,
                       &ldsSel[wv][0], lane, ri, gc * 4, bi, ub, sigma2);
  }
  __syncthreads();

  for (int e = t; e < 32 * TS; e += 256) {
    float dv = accD[e];
    if (dv != 0.f) {
      int r = e / TS, c = e - r * TS;
      int gp = (bi + r) * 384 + ub + c;
      atomicAdd(&num[gp], accN[e]);
      atomicAdd(&den[gp], dv);
    }
  }
}

__global__ void div_kernel(const float* __restrict__ num,
                           const float* __restrict__ den,
                           float* __restrict__ out, int npix) {
  int i = blockIdx.x * blockDim.x + threadIdx.x;
  if (i < npix) out[i] = num[i] / fmaxf(den[i], 1e-8f);
}

extern "C" void kernel_launch(void* const* d_in, const int* in_sizes, int n_in,
                              void* d_out, int out_size, void* d_ws, size_t ws_size,
                              hipStream_t stream) {
  const int* img  = (const int*)d_in[0];
  const int* pvar = (const int*)d_in[1];
  float* out = (float*)d_out;
  float* ws  = (float*)d_ws;

  const int NPIX = 384 * 384;
  float* num1  = ws + 0 * NPIX;
  float* den1  = ws + 1 * NPIX;
  float* basic = ws + 2 * NPIX;
  float* num2  = ws + 3 * NPIX;
  float* den2  = ws + 4 * NPIX;

  hipMemsetAsync(num1, 0, (size_t)2 * NPIX * sizeof(float), stream);
  hipMemsetAsync(num2, 0, (size_t)2 * NPIX * sizeof(float), stream);

  const int NBLK = 95 * 24;   // 95 rows x 24 col-blocks (4 groups each)
  bm3d_pass<0><<<NBLK, 256, 0, stream>>>(img, nullptr, pvar, num1, den1);
  div_kernel<<<(NPIX + 255) / 256, 256, 0, stream>>>(num1, den1, basic, NPIX);
  bm3d_pass<1><<<NBLK, 256, 0, stream>>>(img, basic, pvar, num2, den2);
  div_kernel<<<(NPIX + 255) / 256, 256, 0, stream>>>(num2, den2, out, NPIX);
}